// Round 2
// baseline (99708.081 us; speedup 1.0000x reference)
//
#include <hip/hip_runtime.h>

#define HD  1024
#define SEQ 512
#define NB  32
#define G3  3072          // 3*HD
#define MR  16384         // NB*SEQ

__device__ __forceinline__ float sigmoidf_(float v) { return 1.0f / (1.0f + __expf(-v)); }

// ---------------------------------------------------------------------------
// xi GEMM: C[m][g] = sum_k A[m][k]*W[g][k] + bias[g]
// A:[16384,1024] row-major, W:[3072,1024] row-major (both K-contiguous), C:[16384,3072]
// grid (128,24), block 256, 128x128 tile, BK=16, 8x8 per thread.
// ---------------------------------------------------------------------------
__global__ __launch_bounds__(256, 2) void gemm_xi(const float* __restrict__ A,
                                                  const float* __restrict__ W,
                                                  const float* __restrict__ bias,
                                                  float* __restrict__ C)
{
    __shared__ float As[16][132];   // +4 pad keeps 16B alignment, kills conflicts
    __shared__ float Ws[16][132];

    const int t  = threadIdx.x;
    const int m0 = blockIdx.x * 128;
    const int n0 = blockIdx.y * 128;
    const int tx = t & 15;
    const int ty = t >> 4;
    const int lr = t >> 2;   // 0..63 (row within tile)
    const int kq = t & 3;    // 0..3  (16B chunk within BK)

    float acc[8][8];
#pragma unroll
    for (int i = 0; i < 8; ++i)
#pragma unroll
        for (int j = 0; j < 8; ++j) acc[i][j] = 0.0f;

    const float* Ap = A + (size_t)(m0 + lr) * HD + kq * 4;
    const float* Wp = W + (size_t)(n0 + lr) * HD + kq * 4;

    for (int k0 = 0; k0 < HD; k0 += 16) {
        float4 a0 = *(const float4*)(Ap + k0);
        float4 a1 = *(const float4*)(Ap + (size_t)64 * HD + k0);
        float4 w0 = *(const float4*)(Wp + k0);
        float4 w1 = *(const float4*)(Wp + (size_t)64 * HD + k0);
        __syncthreads();   // previous iteration's compute done before overwrite
        As[kq*4+0][lr]    = a0.x; As[kq*4+1][lr]    = a0.y;
        As[kq*4+2][lr]    = a0.z; As[kq*4+3][lr]    = a0.w;
        As[kq*4+0][lr+64] = a1.x; As[kq*4+1][lr+64] = a1.y;
        As[kq*4+2][lr+64] = a1.z; As[kq*4+3][lr+64] = a1.w;
        Ws[kq*4+0][lr]    = w0.x; Ws[kq*4+1][lr]    = w0.y;
        Ws[kq*4+2][lr]    = w0.z; Ws[kq*4+3][lr]    = w0.w;
        Ws[kq*4+0][lr+64] = w1.x; Ws[kq*4+1][lr+64] = w1.y;
        Ws[kq*4+2][lr+64] = w1.z; Ws[kq*4+3][lr+64] = w1.w;
        __syncthreads();
#pragma unroll
        for (int k = 0; k < 16; ++k) {
            float4 av0 = *(const float4*)(&As[k][ty*8]);
            float4 av1 = *(const float4*)(&As[k][ty*8+4]);
            float4 bv0 = *(const float4*)(&Ws[k][tx*8]);
            float4 bv1 = *(const float4*)(&Ws[k][tx*8+4]);
            float a[8]  = {av0.x, av0.y, av0.z, av0.w, av1.x, av1.y, av1.z, av1.w};
            float bb[8] = {bv0.x, bv0.y, bv0.z, bv0.w, bv1.x, bv1.y, bv1.z, bv1.w};
#pragma unroll
            for (int i = 0; i < 8; ++i)
#pragma unroll
                for (int j = 0; j < 8; ++j)
                    acc[i][j] = fmaf(a[i], bb[j], acc[i][j]);
        }
    }

    float4 bb0 = *(const float4*)(bias + n0 + tx*8);
    float4 bb1 = *(const float4*)(bias + n0 + tx*8 + 4);
    const float bv[8] = {bb0.x, bb0.y, bb0.z, bb0.w, bb1.x, bb1.y, bb1.z, bb1.w};
#pragma unroll
    for (int i = 0; i < 8; ++i) {
        float* crow = C + (size_t)(m0 + ty*8 + i) * G3 + n0 + tx*8;
        float4 o0 = {acc[i][0]+bv[0], acc[i][1]+bv[1], acc[i][2]+bv[2], acc[i][3]+bv[3]};
        float4 o1 = {acc[i][4]+bv[4], acc[i][5]+bv[5], acc[i][6]+bv[6], acc[i][7]+bv[7]};
        *(float4*)(crow)     = o0;
        *(float4*)(crow + 4) = o1;
    }
}

// ---------------------------------------------------------------------------
// One GRU timestep. grid 128, block 256. Block owns 8 h-columns x all 32 b.
// thread (b, jc): 3 dot products over h_prev (K=1024) + gate math.
// USE_XI: xi precomputed (includes bi). Else: also dot x_t against Wi rows.
// ---------------------------------------------------------------------------
template <bool USE_XI>
__global__ __launch_bounds__(256) void gru_step(const float* __restrict__ xi,
                                                const float* __restrict__ xsrc,
                                                const float* __restrict__ Wi,
                                                const float* __restrict__ bi,
                                                const float* __restrict__ Wh,
                                                const float* __restrict__ bh,
                                                const float* __restrict__ hprev,
                                                float* __restrict__ hnext,
                                                float* __restrict__ y,
                                                int t)
{
    const int tid = threadIdx.x;
    const int b   = tid >> 3;          // 0..31
    const int jc  = tid & 7;           // 0..7
    const int j   = blockIdx.x * 8 + jc;

    const float* hp = hprev + (size_t)b * HD;
    const float* wr = Wh + (size_t)j * HD;
    const float* wz = Wh + (size_t)(HD + j) * HD;
    const float* wn = Wh + (size_t)(2*HD + j) * HD;

    float4 ar = {0,0,0,0}, az = {0,0,0,0}, an = {0,0,0,0};
#pragma unroll 4
    for (int k = 0; k < HD; k += 4) {
        float4 h4 = *(const float4*)(hp + k);
        float4 r4 = *(const float4*)(wr + k);
        float4 z4 = *(const float4*)(wz + k);
        float4 n4 = *(const float4*)(wn + k);
        ar.x = fmaf(h4.x, r4.x, ar.x); ar.y = fmaf(h4.y, r4.y, ar.y);
        ar.z = fmaf(h4.z, r4.z, ar.z); ar.w = fmaf(h4.w, r4.w, ar.w);
        az.x = fmaf(h4.x, z4.x, az.x); az.y = fmaf(h4.y, z4.y, az.y);
        az.z = fmaf(h4.z, z4.z, az.z); az.w = fmaf(h4.w, z4.w, az.w);
        an.x = fmaf(h4.x, n4.x, an.x); an.y = fmaf(h4.y, n4.y, an.y);
        an.z = fmaf(h4.z, n4.z, an.z); an.w = fmaf(h4.w, n4.w, an.w);
    }
    float dr = (ar.x + ar.y) + (ar.z + ar.w);
    float dz = (az.x + az.y) + (az.z + az.w);
    float dn = (an.x + an.y) + (an.z + an.w);

    const size_t row = (size_t)b * SEQ + t;
    float xr, xz, xn;
    if (USE_XI) {
        const float* xrow = xi + row * G3;
        xr = xrow[j]; xz = xrow[HD + j]; xn = xrow[2*HD + j];
    } else {
        const float* xp = xsrc + row * HD;
        const float* ur = Wi + (size_t)j * HD;
        const float* uz = Wi + (size_t)(HD + j) * HD;
        const float* un = Wi + (size_t)(2*HD + j) * HD;
        float4 xar = {0,0,0,0}, xaz = {0,0,0,0}, xan = {0,0,0,0};
#pragma unroll 4
        for (int k = 0; k < HD; k += 4) {
            float4 x4 = *(const float4*)(xp + k);
            float4 r4 = *(const float4*)(ur + k);
            float4 z4 = *(const float4*)(uz + k);
            float4 n4 = *(const float4*)(un + k);
            xar.x = fmaf(x4.x, r4.x, xar.x); xar.y = fmaf(x4.y, r4.y, xar.y);
            xar.z = fmaf(x4.z, r4.z, xar.z); xar.w = fmaf(x4.w, r4.w, xar.w);
            xaz.x = fmaf(x4.x, z4.x, xaz.x); xaz.y = fmaf(x4.y, z4.y, xaz.y);
            xaz.z = fmaf(x4.z, z4.z, xaz.z); xaz.w = fmaf(x4.w, z4.w, xaz.w);
            xan.x = fmaf(x4.x, n4.x, xan.x); xan.y = fmaf(x4.y, n4.y, xan.y);
            xan.z = fmaf(x4.z, n4.z, xan.z); xan.w = fmaf(x4.w, n4.w, xan.w);
        }
        xr = (xar.x + xar.y) + (xar.z + xar.w) + bi[j];
        xz = (xaz.x + xaz.y) + (xaz.z + xaz.w) + bi[HD + j];
        xn = (xan.x + xan.y) + (xan.z + xan.w) + bi[2*HD + j];
    }

    float hr = dr + bh[j];
    float hz = dz + bh[HD + j];
    float hn = dn + bh[2*HD + j];
    float r  = sigmoidf_(xr + hr);
    float z  = sigmoidf_(xz + hz);
    float n  = tanhf(xn + r * hn);
    float hpv  = hp[j];
    float hnew = z * hpv + (1.0f - z) * n;

    hnext[(size_t)b * HD + j] = hnew;
    y[row * HD + j]           = hnew;
}

// strided [32,1024] copy (h init / finals). grid 32, block 256.
__global__ __launch_bounds__(256) void copy_h(float* __restrict__ dst, int dstride,
                                              const float* __restrict__ src, int sstride)
{
    const int b = blockIdx.x;
    const int t = threadIdx.x;
    *(float4*)(dst + (size_t)b * dstride + t * 4) =
        *(const float4*)(src + (size_t)b * sstride + t * 4);
}

__global__ __launch_bounds__(256) void copy_f4(float4* __restrict__ dst,
                                               const float4* __restrict__ src, int n4)
{
    int i = blockIdx.x * blockDim.x + threadIdx.x;
    if (i < n4) dst[i] = src[i];
}

// ---------------------------------------------------------------------------
extern "C" void kernel_launch(void* const* d_in, const int* in_sizes, int n_in,
                              void* d_out, int out_size, void* d_ws, size_t ws_size,
                              hipStream_t stream)
{
    const float* x  = (const float*)d_in[0];   // [32,512,1024]
    const float* h0 = (const float*)d_in[1];   // [32,2,1024]
    const float* Wi = (const float*)d_in[2];   // [2,3072,1024]
    const float* bi = (const float*)d_in[3];   // [2,3072]
    const float* Wh = (const float*)d_in[4];   // [2,3072,1024]
    const float* bh = (const float*)d_in[5];   // [2,3072]

    float* y   = (float*)d_out;                // [32,512,1024]
    float* fin = y + (size_t)MR * HD;          // [32,2,1024]

    const size_t xi_elems   = (size_t)MR * G3;     // 50,331,648 floats (~201MB)
    const size_t hbuf_elems = (size_t)NB * HD;     // 32768

    // Workspace tiers (ws_size unknown a priori; adapt, same plan every call):
    float* xi    = nullptr;   // Tier A: precomputed input gates
    float* xsrc1 = nullptr;   // Tier B: copy of layer-0 output for layer-1 fused path
    float* hA;
    if (ws_size >= (xi_elems + 2 * hbuf_elems) * sizeof(float)) {
        xi = (float*)d_ws;
        hA = xi + xi_elems;
    } else if (ws_size >= ((size_t)MR * HD + 2 * hbuf_elems) * sizeof(float)) {
        xsrc1 = (float*)d_ws;
        hA = xsrc1 + (size_t)MR * HD;
    } else {
        hA = (float*)d_ws;    // minimal: just the two h ping-pong buffers
    }
    float* hB = hA + hbuf_elems;

    for (int l = 0; l < 2; ++l) {
        const float* src = (l == 0) ? x : (const float*)y;
        if (l == 1 && xsrc1 != nullptr) {
            // fused path would otherwise read and write y in the same kernel
            copy_f4<<<dim3(MR * HD / 4 / 256), 256, 0, stream>>>(
                (float4*)xsrc1, (const float4*)y, MR * HD / 4);
            src = xsrc1;
        }
        const float* Wi_l = Wi + (size_t)l * G3 * HD;
        const float* bi_l = bi + (size_t)l * G3;
        const float* Wh_l = Wh + (size_t)l * G3 * HD;
        const float* bh_l = bh + (size_t)l * G3;

        if (xi != nullptr)
            gemm_xi<<<dim3(128, 24), 256, 0, stream>>>(src, Wi_l, bi_l, xi);

        // init h state from input h[:, l, :]
        copy_h<<<NB, 256, 0, stream>>>(hA, HD, h0 + (size_t)l * HD, 2 * HD);

        float* hp = hA;
        float* hn = hB;
        for (int tt = 0; tt < SEQ; ++tt) {
            if (xi != nullptr)
                gru_step<true><<<128, 256, 0, stream>>>(xi, src, Wi_l, bi_l, Wh_l, bh_l,
                                                        hp, hn, y, tt);
            else
                gru_step<false><<<128, 256, 0, stream>>>(nullptr, src, Wi_l, bi_l, Wh_l, bh_l,
                                                         hp, hn, y, tt);
            float* tmp = hp; hp = hn; hn = tmp;
        }
        // final hidden state -> fin[:, l, :]
        copy_h<<<NB, 256, 0, stream>>>(fin + (size_t)l * HD, 2 * HD, hp, HD);
    }
}

// Round 3
// 30585.303 us; speedup vs baseline: 3.2600x; 3.2600x over previous
//
#include <hip/hip_runtime.h>

#define HD   1024
#define SEQ  512
#define NB   32
#define G3   3072          // 3*HD
#define MR   16384         // NB*SEQ
#define PBLK 256           // persistent grid = one block per CU

__device__ __forceinline__ float sigmoidf_(float v) { return 1.0f / (1.0f + __expf(-v)); }

// ---------------------------------------------------------------------------
// xi GEMM: C[m][g] = sum_k A[m][k]*W[g][k] + bias[g]
// A:[16384,1024], W:[3072,1024] (both K-contiguous), C:[16384,3072]
// grid (128,24), block 256, 128x128 tile, BK=16, 8x8 per thread.
// ---------------------------------------------------------------------------
__global__ __launch_bounds__(256, 2) void gemm_xi(const float* __restrict__ A,
                                                  const float* __restrict__ W,
                                                  const float* __restrict__ bias,
                                                  float* __restrict__ C)
{
    __shared__ float As[16][132];
    __shared__ float Ws[16][132];

    const int t  = threadIdx.x;
    const int m0 = blockIdx.x * 128;
    const int n0 = blockIdx.y * 128;
    const int tx = t & 15;
    const int ty = t >> 4;
    const int lr = t >> 2;
    const int kq = t & 3;

    float acc[8][8];
#pragma unroll
    for (int i = 0; i < 8; ++i)
#pragma unroll
        for (int j = 0; j < 8; ++j) acc[i][j] = 0.0f;

    const float* Ap = A + (size_t)(m0 + lr) * HD + kq * 4;
    const float* Wp = W + (size_t)(n0 + lr) * HD + kq * 4;

    for (int k0 = 0; k0 < HD; k0 += 16) {
        float4 a0 = *(const float4*)(Ap + k0);
        float4 a1 = *(const float4*)(Ap + (size_t)64 * HD + k0);
        float4 w0 = *(const float4*)(Wp + k0);
        float4 w1 = *(const float4*)(Wp + (size_t)64 * HD + k0);
        __syncthreads();
        As[kq*4+0][lr]    = a0.x; As[kq*4+1][lr]    = a0.y;
        As[kq*4+2][lr]    = a0.z; As[kq*4+3][lr]    = a0.w;
        As[kq*4+0][lr+64] = a1.x; As[kq*4+1][lr+64] = a1.y;
        As[kq*4+2][lr+64] = a1.z; As[kq*4+3][lr+64] = a1.w;
        Ws[kq*4+0][lr]    = w0.x; Ws[kq*4+1][lr]    = w0.y;
        Ws[kq*4+2][lr]    = w0.z; Ws[kq*4+3][lr]    = w0.w;
        Ws[kq*4+0][lr+64] = w1.x; Ws[kq*4+1][lr+64] = w1.y;
        Ws[kq*4+2][lr+64] = w1.z; Ws[kq*4+3][lr+64] = w1.w;
        __syncthreads();
#pragma unroll
        for (int k = 0; k < 16; ++k) {
            float4 av0 = *(const float4*)(&As[k][ty*8]);
            float4 av1 = *(const float4*)(&As[k][ty*8+4]);
            float4 bv0 = *(const float4*)(&Ws[k][tx*8]);
            float4 bv1 = *(const float4*)(&Ws[k][tx*8+4]);
            float a[8]  = {av0.x, av0.y, av0.z, av0.w, av1.x, av1.y, av1.z, av1.w};
            float bb[8] = {bv0.x, bv0.y, bv0.z, bv0.w, bv1.x, bv1.y, bv1.z, bv1.w};
#pragma unroll
            for (int i = 0; i < 8; ++i)
#pragma unroll
                for (int j = 0; j < 8; ++j)
                    acc[i][j] = fmaf(a[i], bb[j], acc[i][j]);
        }
    }

    float4 bb0 = *(const float4*)(bias + n0 + tx*8);
    float4 bb1 = *(const float4*)(bias + n0 + tx*8 + 4);
    const float bv[8] = {bb0.x, bb0.y, bb0.z, bb0.w, bb1.x, bb1.y, bb1.z, bb1.w};
#pragma unroll
    for (int i = 0; i < 8; ++i) {
        float* crow = C + (size_t)(m0 + ty*8 + i) * G3 + n0 + tx*8;
        float4 o0 = {acc[i][0]+bv[0], acc[i][1]+bv[1], acc[i][2]+bv[2], acc[i][3]+bv[3]};
        float4 o1 = {acc[i][4]+bv[4], acc[i][5]+bv[5], acc[i][6]+bv[6], acc[i][7]+bv[7]};
        *(float4*)(crow)     = o0;
        *(float4*)(crow + 4) = o1;
    }
}

// ---------------------------------------------------------------------------
// Persistent GRU recurrence: 256 blocks (1/CU, forced by 132KB LDS), 512 steps
// with manual grid barrier. Wave w of block bk owns h-column j = bk*4+w and
// its 3 gate rows, held in registers (lane p<16 holds W[row][p+16i], i<64).
// Per step: stage h[32][1024] -> LDS; 8 passes x (4 batches per 16-lane group):
// 64 ds_read + 192 FMA + 4-level shfl_xor reduce; gate math; h_new stored
// write-through (agent-scope atomic store) so the relaxed-counter barrier
// needs no L2 writeback; acquire fence invalidates before next stage.
// ---------------------------------------------------------------------------
__global__ __launch_bounds__(256, 1) void gru_persist(const float* __restrict__ xi,
                                                      const float* __restrict__ Wh,
                                                      const float* __restrict__ bh,
                                                      const float* __restrict__ h0,
                                                      float* __restrict__ y,
                                                      float* __restrict__ fin,
                                                      float* __restrict__ hb0,
                                                      float* __restrict__ hb1,
                                                      unsigned* __restrict__ counter,
                                                      int layer)
{
    __shared__ float hs[NB][HD + 8];   // +8 pad: 16-lane groups land 2-way (free)

    const int tid = threadIdx.x;
    const int w   = tid >> 6;          // wave 0..3
    const int l   = tid & 63;
    const int p   = l & 15;            // k-slice position within 16-lane group
    const int g   = l >> 4;            // batch group 0..3
    const int j   = blockIdx.x * 4 + w;

    // --- weights into registers (once) ---
    float w0[64], w1[64], w2[64];
    {
        const float* W0 = Wh + (size_t)j * HD + p;
        const float* W1 = Wh + (size_t)(HD + j) * HD + p;
        const float* W2 = Wh + (size_t)(2*HD + j) * HD + p;
#pragma unroll
        for (int i = 0; i < 64; ++i) {
            w0[i] = W0[16*i];
            w1[i] = W1[16*i];
            w2[i] = W2[16*i];
        }
    }
    const float bhr = bh[j], bhz = bh[HD + j], bhn = bh[2*HD + j];

    const int sr = tid >> 3;   // staging: batch row 0..31
    const int sq = tid & 7;    // staging: 1/8 of the row

    for (int t = 0; t < SEQ; ++t) {
        // xi prefetch (overlaps staging): lane holds 3 gate values for batch l&31
        const int bx = l & 31;
        const float* xrow = xi + ((size_t)bx * SEQ + t) * G3;
        float xv0 = xrow[j];
        float xv1 = xrow[HD + j];
        float xv2 = xrow[2*HD + j];

        // stage h_prev -> LDS (t==0: from h0 input, stride 2H)
        {
            const float* src;
            int sstride;
            if (t == 0) { src = h0 + (size_t)layer * HD; sstride = 2 * HD; }
            else        { src = (t & 1) ? hb0 : hb1;     sstride = HD; }
            const float* s0 = src + (size_t)sr * sstride + sq * 4;
#pragma unroll 8
            for (int c = 0; c < 32; ++c) {
                float4 v = *(const float4*)(s0 + c * 32);
                *(float4*)(&hs[sr][(sq + 8*c) * 4]) = v;
            }
        }
        __syncthreads();

        float* hbw = (t & 1) ? hb1 : hb0;

#pragma unroll 2
        for (int pass = 0; pass < 8; ++pass) {
            const int bg = pass * 4 + g;
            float hq[64];
#pragma unroll
            for (int i = 0; i < 64; ++i) hq[i] = hs[bg][p + 16*i];
            float a0 = 0.f, a1 = 0.f, a2 = 0.f;
#pragma unroll
            for (int i = 0; i < 64; ++i) {
                a0 = fmaf(w0[i], hq[i], a0);
                a1 = fmaf(w1[i], hq[i], a1);
                a2 = fmaf(w2[i], hq[i], a2);
            }
#pragma unroll
            for (int m = 1; m <= 8; m <<= 1) {
                a0 += __shfl_xor(a0, m);
                a1 += __shfl_xor(a1, m);
                a2 += __shfl_xor(a2, m);
            }
            float xr = __shfl(xv0, bg);
            float xz = __shfl(xv1, bg);
            float xn = __shfl(xv2, bg);
            float rr = sigmoidf_(xr + a0 + bhr);
            float zz = sigmoidf_(xz + a1 + bhz);
            float hp = hs[bg][j];
            float e  = __expf(2.0f * (xn + rr * (a2 + bhn)));
            float nn = 1.0f - 2.0f / (e + 1.0f);   // tanh
            float hnew = zz * hp + (1.0f - zz) * nn;
            if (p == 0) {
                // write-through to coherence point: barrier needs no L2 writeback
                __hip_atomic_store(hbw + (size_t)bg * HD + j, hnew,
                                   __ATOMIC_RELAXED, __HIP_MEMORY_SCOPE_AGENT);
                y[((size_t)bg * SEQ + t) * HD + j] = hnew;
                if (t == SEQ - 1)
                    fin[(size_t)bg * (2*HD) + (size_t)layer * HD + j] = hnew;
            }
        }

        if (t < SEQ - 1) {
            __syncthreads();   // drains vmcnt(0): h stores complete at LLC
            if (tid == 0) {
                __hip_atomic_fetch_add(counter, 1u, __ATOMIC_RELAXED,
                                       __HIP_MEMORY_SCOPE_AGENT);
                const unsigned tgt = (unsigned)(PBLK * (t + 1));
                while (__hip_atomic_load(counter, __ATOMIC_RELAXED,
                                         __HIP_MEMORY_SCOPE_AGENT) < tgt)
                    __builtin_amdgcn_s_sleep(1);
            }
            __syncthreads();
            __builtin_amdgcn_fence(__ATOMIC_ACQUIRE, "agent");  // invalidate L1/L2
        }
    }
}

// --------------------------- fallback path (small ws) -----------------------
template <bool USE_XI>
__global__ __launch_bounds__(256) void gru_step(const float* __restrict__ xi,
                                                const float* __restrict__ xsrc,
                                                const float* __restrict__ Wi,
                                                const float* __restrict__ bi,
                                                const float* __restrict__ Wh,
                                                const float* __restrict__ bh,
                                                const float* __restrict__ hprev,
                                                float* __restrict__ hnext,
                                                float* __restrict__ y,
                                                int t)
{
    const int tid = threadIdx.x;
    const int b   = tid >> 3;
    const int jc  = tid & 7;
    const int j   = blockIdx.x * 8 + jc;

    const float* hp = hprev + (size_t)b * HD;
    const float* wr = Wh + (size_t)j * HD;
    const float* wz = Wh + (size_t)(HD + j) * HD;
    const float* wn = Wh + (size_t)(2*HD + j) * HD;

    float4 ar = {0,0,0,0}, az = {0,0,0,0}, an = {0,0,0,0};
#pragma unroll 4
    for (int k = 0; k < HD; k += 4) {
        float4 h4 = *(const float4*)(hp + k);
        float4 r4 = *(const float4*)(wr + k);
        float4 z4 = *(const float4*)(wz + k);
        float4 n4 = *(const float4*)(wn + k);
        ar.x = fmaf(h4.x, r4.x, ar.x); ar.y = fmaf(h4.y, r4.y, ar.y);
        ar.z = fmaf(h4.z, r4.z, ar.z); ar.w = fmaf(h4.w, r4.w, ar.w);
        az.x = fmaf(h4.x, z4.x, az.x); az.y = fmaf(h4.y, z4.y, az.y);
        az.z = fmaf(h4.z, z4.z, az.z); az.w = fmaf(h4.w, z4.w, az.w);
        an.x = fmaf(h4.x, n4.x, an.x); an.y = fmaf(h4.y, n4.y, an.y);
        an.z = fmaf(h4.z, n4.z, an.z); an.w = fmaf(h4.w, n4.w, an.w);
    }
    float dr = (ar.x + ar.y) + (ar.z + ar.w);
    float dz = (az.x + az.y) + (az.z + az.w);
    float dn = (an.x + an.y) + (an.z + an.w);

    const size_t row = (size_t)b * SEQ + t;
    float xr, xz, xn;
    if (USE_XI) {
        const float* xrow = xi + row * G3;
        xr = xrow[j]; xz = xrow[HD + j]; xn = xrow[2*HD + j];
    } else {
        const float* xp = xsrc + row * HD;
        const float* ur = Wi + (size_t)j * HD;
        const float* uz = Wi + (size_t)(HD + j) * HD;
        const float* un = Wi + (size_t)(2*HD + j) * HD;
        float4 xar = {0,0,0,0}, xaz = {0,0,0,0}, xan = {0,0,0,0};
#pragma unroll 4
        for (int k = 0; k < HD; k += 4) {
            float4 x4 = *(const float4*)(xp + k);
            float4 r4 = *(const float4*)(ur + k);
            float4 z4 = *(const float4*)(uz + k);
            float4 n4 = *(const float4*)(un + k);
            xar.x = fmaf(x4.x, r4.x, xar.x); xar.y = fmaf(x4.y, r4.y, xar.y);
            xar.z = fmaf(x4.z, r4.z, xar.z); xar.w = fmaf(x4.w, r4.w, xar.w);
            xaz.x = fmaf(x4.x, z4.x, xaz.x); xaz.y = fmaf(x4.y, z4.y, xaz.y);
            xaz.z = fmaf(x4.z, z4.z, xaz.z); xaz.w = fmaf(x4.w, z4.w, xaz.w);
            xan.x = fmaf(x4.x, n4.x, xan.x); xan.y = fmaf(x4.y, n4.y, xan.y);
            xan.z = fmaf(x4.z, n4.z, xan.z); xan.w = fmaf(x4.w, n4.w, xan.w);
        }
        xr = (xar.x + xar.y) + (xar.z + xar.w) + bi[j];
        xz = (xaz.x + xaz.y) + (xaz.z + xaz.w) + bi[HD + j];
        xn = (xan.x + xan.y) + (xan.z + xan.w) + bi[2*HD + j];
    }

    float hr = dr + bh[j];
    float hz = dz + bh[HD + j];
    float hn = dn + bh[2*HD + j];
    float r  = sigmoidf_(xr + hr);
    float z  = sigmoidf_(xz + hz);
    float n  = tanhf(xn + r * hn);
    float hpv  = hp[j];
    float hnew = z * hpv + (1.0f - z) * n;

    hnext[(size_t)b * HD + j] = hnew;
    y[row * HD + j]           = hnew;
}

__global__ __launch_bounds__(256) void copy_h(float* __restrict__ dst, int dstride,
                                              const float* __restrict__ src, int sstride)
{
    const int b = blockIdx.x;
    const int t = threadIdx.x;
    *(float4*)(dst + (size_t)b * dstride + t * 4) =
        *(const float4*)(src + (size_t)b * sstride + t * 4);
}

__global__ __launch_bounds__(256) void copy_f4(float4* __restrict__ dst,
                                               const float4* __restrict__ src, int n4)
{
    int i = blockIdx.x * blockDim.x + threadIdx.x;
    if (i < n4) dst[i] = src[i];
}

// ---------------------------------------------------------------------------
extern "C" void kernel_launch(void* const* d_in, const int* in_sizes, int n_in,
                              void* d_out, int out_size, void* d_ws, size_t ws_size,
                              hipStream_t stream)
{
    const float* x  = (const float*)d_in[0];   // [32,512,1024]
    const float* h0 = (const float*)d_in[1];   // [32,2,1024]
    const float* Wi = (const float*)d_in[2];   // [2,3072,1024]
    const float* bi = (const float*)d_in[3];   // [2,3072]
    const float* Wh = (const float*)d_in[4];   // [2,3072,1024]
    const float* bh = (const float*)d_in[5];   // [2,3072]

    float* y   = (float*)d_out;                // [32,512,1024]
    float* fin = y + (size_t)MR * HD;          // [32,2,1024]

    const size_t xi_elems   = (size_t)MR * G3;     // ~201MB
    const size_t hbuf_elems = (size_t)NB * HD;     // 32768
    const size_t need_persist = 256 + (xi_elems + 2 * hbuf_elems) * sizeof(float);

    if (ws_size >= need_persist) {
        // counters[0..1] at base (re-zeroed every call; ws is poisoned 0xAA)
        unsigned* counters = (unsigned*)d_ws;
        float* xi  = (float*)((char*)d_ws + 256);
        float* hb0 = xi + xi_elems;
        float* hb1 = hb0 + hbuf_elems;
        hipMemsetAsync(d_ws, 0, 256, stream);

        for (int l = 0; l < 2; ++l) {
            const float* src  = (l == 0) ? x : (const float*)y;
            const float* Wi_l = Wi + (size_t)l * G3 * HD;
            const float* bi_l = bi + (size_t)l * G3;
            const float* Wh_l = Wh + (size_t)l * G3 * HD;
            const float* bh_l = bh + (size_t)l * G3;

            gemm_xi<<<dim3(128, 24), 256, 0, stream>>>(src, Wi_l, bi_l, xi);
            gru_persist<<<PBLK, 256, 0, stream>>>(xi, Wh_l, bh_l, h0, y, fin,
                                                  hb0, hb1, counters + l, l);
        }
        return;
    }

    // ---------------- fallback: per-step launches (round-2 baseline) --------
    float* xi    = nullptr;
    float* xsrc1 = nullptr;
    float* hA;
    if (ws_size >= (xi_elems + 2 * hbuf_elems) * sizeof(float)) {
        xi = (float*)d_ws;
        hA = xi + xi_elems;
    } else if (ws_size >= ((size_t)MR * HD + 2 * hbuf_elems) * sizeof(float)) {
        xsrc1 = (float*)d_ws;
        hA = xsrc1 + (size_t)MR * HD;
    } else {
        hA = (float*)d_ws;
    }
    float* hB = hA + hbuf_elems;

    for (int l = 0; l < 2; ++l) {
        const float* src = (l == 0) ? x : (const float*)y;
        if (l == 1 && xsrc1 != nullptr) {
            copy_f4<<<dim3(MR * HD / 4 / 256), 256, 0, stream>>>(
                (float4*)xsrc1, (const float4*)y, MR * HD / 4);
            src = xsrc1;
        }
        const float* Wi_l = Wi + (size_t)l * G3 * HD;
        const float* bi_l = bi + (size_t)l * G3;
        const float* Wh_l = Wh + (size_t)l * G3 * HD;
        const float* bh_l = bh + (size_t)l * G3;

        if (xi != nullptr)
            gemm_xi<<<dim3(128, 24), 256, 0, stream>>>(src, Wi_l, bi_l, xi);

        copy_h<<<NB, 256, 0, stream>>>(hA, HD, h0 + (size_t)l * HD, 2 * HD);

        float* hp = hA;
        float* hn = hB;
        for (int tt = 0; tt < SEQ; ++tt) {
            if (xi != nullptr)
                gru_step<true><<<128, 256, 0, stream>>>(xi, src, Wi_l, bi_l, Wh_l, bh_l,
                                                        hp, hn, y, tt);
            else
                gru_step<false><<<128, 256, 0, stream>>>(nullptr, src, Wi_l, bi_l, Wh_l, bh_l,
                                                         hp, hn, y, tt);
            float* tmp = hp; hp = hn; hn = tmp;
        }
        copy_h<<<NB, 256, 0, stream>>>(fin + (size_t)l * HD, 2 * HD, hp, HD);
    }
}

// Round 6
// 20376.279 us; speedup vs baseline: 4.8933x; 1.5010x over previous
//
#include <hip/hip_runtime.h>

#define HD    1024
#define SEQ   512
#define NB    32
#define G3    3072          // 3*HD
#define MR    16384         // NB*SEQ
#define PBLK2 512           // persistent grid: 2 blocks/CU guaranteed co-resident

__device__ __forceinline__ float sigmoidf_(float v) { return 1.0f / (1.0f + __expf(-v)); }

// DPP-based wave64 sum reduction: VALU pipe only (no DS-pipe shuffles).
// quad_perm xor1, xor2, half_mirror(~xor4), mirror(~xor8), bcast15, bcast31.
#define DPP_XADD(acc, ctrl, rmask)                                              \
    acc += __int_as_float(__builtin_amdgcn_update_dpp(                          \
        0, __float_as_int(acc), ctrl, rmask, 0xf, false))

__device__ __forceinline__ float wave_reduce_sum(float a)
{
    DPP_XADD(a, 0xB1,  0xF);   // quad_perm [1,0,3,2]  : + lane^1
    DPP_XADD(a, 0x4E,  0xF);   // quad_perm [2,3,0,1]  : + lane^2
    DPP_XADD(a, 0x141, 0xF);   // row_half_mirror      : + within-8 pair
    DPP_XADD(a, 0x140, 0xF);   // row_mirror           : + within-16 pair
    DPP_XADD(a, 0x142, 0xA);   // row_bcast15 -> rows 1,3
    DPP_XADD(a, 0x143, 0xC);   // row_bcast31 -> rows 2,3 (lane63 = full sum)
    return __int_as_float(__builtin_amdgcn_readlane(__float_as_int(a), 63));
}

// ---------------------------------------------------------------------------
// xi GEMM: C[m][g] = sum_k A[m][k]*W[g][k] + bias[g]   (unchanged from r2)
// ---------------------------------------------------------------------------
__global__ __launch_bounds__(256, 2) void gemm_xi(const float* __restrict__ A,
                                                  const float* __restrict__ W,
                                                  const float* __restrict__ bias,
                                                  float* __restrict__ C)
{
    __shared__ float As[16][132];
    __shared__ float Ws[16][132];

    const int t  = threadIdx.x;
    const int m0 = blockIdx.x * 128;
    const int n0 = blockIdx.y * 128;
    const int tx = t & 15;
    const int ty = t >> 4;
    const int lr = t >> 2;
    const int kq = t & 3;

    float acc[8][8];
#pragma unroll
    for (int i = 0; i < 8; ++i)
#pragma unroll
        for (int j = 0; j < 8; ++j) acc[i][j] = 0.0f;

    const float* Ap = A + (size_t)(m0 + lr) * HD + kq * 4;
    const float* Wp = W + (size_t)(n0 + lr) * HD + kq * 4;

    for (int k0 = 0; k0 < HD; k0 += 16) {
        float4 a0 = *(const float4*)(Ap + k0);
        float4 a1 = *(const float4*)(Ap + (size_t)64 * HD + k0);
        float4 w0 = *(const float4*)(Wp + k0);
        float4 w1 = *(const float4*)(Wp + (size_t)64 * HD + k0);
        __syncthreads();
        As[kq*4+0][lr]    = a0.x; As[kq*4+1][lr]    = a0.y;
        As[kq*4+2][lr]    = a0.z; As[kq*4+3][lr]    = a0.w;
        As[kq*4+0][lr+64] = a1.x; As[kq*4+1][lr+64] = a1.y;
        As[kq*4+2][lr+64] = a1.z; As[kq*4+3][lr+64] = a1.w;
        Ws[kq*4+0][lr]    = w0.x; Ws[kq*4+1][lr]    = w0.y;
        Ws[kq*4+2][lr]    = w0.z; Ws[kq*4+3][lr]    = w0.w;
        Ws[kq*4+0][lr+64] = w1.x; Ws[kq*4+1][lr+64] = w1.y;
        Ws[kq*4+2][lr+64] = w1.z; Ws[kq*4+3][lr+64] = w1.w;
        __syncthreads();
#pragma unroll
        for (int k = 0; k < 16; ++k) {
            float4 av0 = *(const float4*)(&As[k][ty*8]);
            float4 av1 = *(const float4*)(&As[k][ty*8+4]);
            float4 bv0 = *(const float4*)(&Ws[k][tx*8]);
            float4 bv1 = *(const float4*)(&Ws[k][tx*8+4]);
            float a[8]  = {av0.x, av0.y, av0.z, av0.w, av1.x, av1.y, av1.z, av1.w};
            float bb[8] = {bv0.x, bv0.y, bv0.z, bv0.w, bv1.x, bv1.y, bv1.z, bv1.w};
#pragma unroll
            for (int i = 0; i < 8; ++i)
#pragma unroll
                for (int j = 0; j < 8; ++j)
                    acc[i][j] = fmaf(a[i], bb[j], acc[i][j]);
        }
    }

    float4 bb0 = *(const float4*)(bias + n0 + tx*8);
    float4 bb1 = *(const float4*)(bias + n0 + tx*8 + 4);
    const float bv[8] = {bb0.x, bb0.y, bb0.z, bb0.w, bb1.x, bb1.y, bb1.z, bb1.w};
#pragma unroll
    for (int i = 0; i < 8; ++i) {
        float* crow = C + (size_t)(m0 + ty*8 + i) * G3 + n0 + tx*8;
        float4 o0 = {acc[i][0]+bv[0], acc[i][1]+bv[1], acc[i][2]+bv[2], acc[i][3]+bv[3]};
        float4 o1 = {acc[i][4]+bv[4], acc[i][5]+bv[5], acc[i][6]+bv[6], acc[i][7]+bv[7]};
        *(float4*)(crow)     = o0;
        *(float4*)(crow + 4) = o1;
    }
}

// ---------------------------------------------------------------------------
// Persistent GRU v2. Grid 512 = 256 j-blocks x 2 batch-halves; 256 thr (4 waves).
// __launch_bounds__(256,2): VGPR<=256 + LDS 65KB -> 2 blocks/CU co-resident
// (deadlock-safe), 2 waves/SIMD (DS/VALU overlap).
// Wave w owns column j = (bk>>1)*4+w: 3 gate rows in 48 VGPRs
// (lane l holds k in {256c+4l..+3}, c<4 -> contiguous 16B/lane, conflict-free
// ds_read_b128 against the hs tile). Reduction = DPP chain (VALU pipe).
// Grid barrier: 32 spread counters (16 blocks each) + 32-lane poll by wave 0.
// ---------------------------------------------------------------------------
__global__ __launch_bounds__(256, 2) void gru_persist2(const float* __restrict__ xi,
                                                       const float* __restrict__ Wh,
                                                       const float* __restrict__ bh,
                                                       const float* __restrict__ h0,
                                                       float* __restrict__ y,
                                                       float* __restrict__ fin,
                                                       float* __restrict__ hb0,
                                                       float* __restrict__ hb1,
                                                       unsigned* __restrict__ cnt,
                                                       int layer)
{
    __shared__ float  hs[16 * HD];     // this block's 16-batch slice of h
    __shared__ float4 xis[3][16];      // xi values for (gate, batch) x 4 j's

    const int tid  = threadIdx.x;
    const int bk   = blockIdx.x;
    const int w    = tid >> 6;         // wave 0..3
    const int lane = tid & 63;
    const int bg   = bk & 1;           // batch half
    const int jq   = bk >> 1;          // 0..255
    const int j    = jq * 4 + w;
    const int b0   = bg * 16;

    // --- weights into registers (lane l: k = 256c + 4l, contiguous 16B) ---
    float4 w0[4], w1[4], w2[4];
#pragma unroll
    for (int c = 0; c < 4; ++c) {
        w0[c] = *(const float4*)(Wh + (size_t)j          * HD + 256*c + 4*lane);
        w1[c] = *(const float4*)(Wh + (size_t)(HD + j)   * HD + 256*c + 4*lane);
        w2[c] = *(const float4*)(Wh + (size_t)(2*HD + j) * HD + 256*c + 4*lane);
    }
    const float bhr = bh[j], bhz = bh[HD + j], bhn = bh[2*HD + j];

    for (int t = 0; t < SEQ; ++t) {
        // ---- stage h slice + xi into LDS ----
        if (t == 0) {
            const int r = tid >> 4, pc = tid & 15;
            const float* src = h0 + (size_t)(b0 + r) * (2*HD) + (size_t)layer * HD;
#pragma unroll
            for (int c = 0; c < 16; ++c) {
                const int f4 = pc * 16 + c;
                *(float4*)(hs + (size_t)r * HD + f4 * 4) =
                    *(const float4*)(src + f4 * 4);
            }
        } else {
            const float* src = ((t & 1) ? hb0 : hb1) + (size_t)b0 * HD;
#pragma unroll
            for (int c = 0; c < 16; ++c) {
                const int f4 = c * 256 + tid;          // coalesced 1KB/wave-inst
                *(float4*)(hs + f4 * 4) = *(const float4*)(src + f4 * 4);
            }
        }
        if (tid < 48) {
            const int g = tid >> 4, bl = tid & 15;
            xis[g][bl] = *(const float4*)(xi + ((size_t)(b0 + bl) * SEQ + t) * G3
                                             + g * HD + jq * 4);
        }
        __syncthreads();

        float* hbw = (t & 1) ? hb1 : hb0;

#pragma unroll 4
        for (int b = 0; b < 16; ++b) {
            const float* hp = hs + (size_t)b * HD;
            float ar = 0.f, az = 0.f, an = 0.f;
#pragma unroll
            for (int c = 0; c < 4; ++c) {
                float4 hq = *(const float4*)(hp + 256*c + 4*lane);
                ar = fmaf(w0[c].x, hq.x, ar); ar = fmaf(w0[c].y, hq.y, ar);
                ar = fmaf(w0[c].z, hq.z, ar); ar = fmaf(w0[c].w, hq.w, ar);
                az = fmaf(w1[c].x, hq.x, az); az = fmaf(w1[c].y, hq.y, az);
                az = fmaf(w1[c].z, hq.z, az); az = fmaf(w1[c].w, hq.w, az);
                an = fmaf(w2[c].x, hq.x, an); an = fmaf(w2[c].y, hq.y, an);
                an = fmaf(w2[c].z, hq.z, an); an = fmaf(w2[c].w, hq.w, an);
            }
            const float sr = wave_reduce_sum(ar);
            const float sz = wave_reduce_sum(az);
            const float sn = wave_reduce_sum(an);

            const float xr = ((const float*)&xis[0][b])[w];
            const float xz = ((const float*)&xis[1][b])[w];
            const float xn = ((const float*)&xis[2][b])[w];

            const float rr  = sigmoidf_(xr + sr + bhr);
            const float zz  = sigmoidf_(xz + sz + bhz);
            const float hpv = hp[j];
            const float e   = __expf(2.0f * (xn + rr * (sn + bhn)));
            const float nn  = 1.0f - 2.0f / (e + 1.0f);          // tanh
            const float hnew = zz * hpv + (1.0f - zz) * nn;

            if (lane == 0) {
                __hip_atomic_store(hbw + (size_t)(b0 + b) * HD + j, hnew,
                                   __ATOMIC_RELAXED, __HIP_MEMORY_SCOPE_AGENT);
                y[((size_t)(b0 + b) * SEQ + t) * HD + j] = hnew;
                if (t == SEQ - 1)
                    fin[((size_t)(b0 + b) * 2 + layer) * HD + j] = hnew;
            }
        }

        if (t < SEQ - 1) {
            __syncthreads();                    // drains vmcnt: stores visible
            if (tid == 0)
                __hip_atomic_fetch_add(cnt + (bk & 31) * 16, 1u,
                                       __ATOMIC_RELAXED, __HIP_MEMORY_SCOPE_AGENT);
            if (tid < 64) {                     // wave 0 polls all 32 counters
                const unsigned tgt = 16u * (unsigned)(t + 1);
                for (;;) {
                    unsigned v = tgt;
                    if (lane < 32)
                        v = __hip_atomic_load(cnt + lane * 16, __ATOMIC_RELAXED,
                                              __HIP_MEMORY_SCOPE_AGENT);
                    if (__all((int)(v >= tgt))) break;
                    __builtin_amdgcn_s_sleep(2);
                }
                __builtin_amdgcn_fence(__ATOMIC_ACQUIRE, "agent");  // inv L1/L2
            }
            __syncthreads();
        }
    }
}

// --------------------------- fallback path (small ws) -----------------------
template <bool USE_XI>
__global__ __launch_bounds__(256) void gru_step(const float* __restrict__ xi,
                                                const float* __restrict__ xsrc,
                                                const float* __restrict__ Wi,
                                                const float* __restrict__ bi,
                                                const float* __restrict__ Wh,
                                                const float* __restrict__ bh,
                                                const float* __restrict__ hprev,
                                                float* __restrict__ hnext,
                                                float* __restrict__ y,
                                                int t)
{
    const int tid = threadIdx.x;
    const int b   = tid >> 3;
    const int jc  = tid & 7;
    const int j   = blockIdx.x * 8 + jc;

    const float* hp = hprev + (size_t)b * HD;
    const float* wr = Wh + (size_t)j * HD;
    const float* wz = Wh + (size_t)(HD + j) * HD;
    const float* wn = Wh + (size_t)(2*HD + j) * HD;

    float4 ar = {0,0,0,0}, az = {0,0,0,0}, an = {0,0,0,0};
#pragma unroll 4
    for (int k = 0; k < HD; k += 4) {
        float4 h4 = *(const float4*)(hp + k);
        float4 r4 = *(const float4*)(wr + k);
        float4 z4 = *(const float4*)(wz + k);
        float4 n4 = *(const float4*)(wn + k);
        ar.x = fmaf(h4.x, r4.x, ar.x); ar.y = fmaf(h4.y, r4.y, ar.y);
        ar.z = fmaf(h4.z, r4.z, ar.z); ar.w = fmaf(h4.w, r4.w, ar.w);
        az.x = fmaf(h4.x, z4.x, az.x); az.y = fmaf(h4.y, z4.y, az.y);
        az.z = fmaf(h4.z, z4.z, az.z); az.w = fmaf(h4.w, z4.w, az.w);
        an.x = fmaf(h4.x, n4.x, an.x); an.y = fmaf(h4.y, n4.y, an.y);
        an.z = fmaf(h4.z, n4.z, an.z); an.w = fmaf(h4.w, n4.w, an.w);
    }
    float dr = (ar.x + ar.y) + (ar.z + ar.w);
    float dz = (az.x + az.y) + (az.z + az.w);
    float dn = (an.x + an.y) + (an.z + an.w);

    const size_t row = (size_t)b * SEQ + t;
    float xr, xz, xn;
    if (USE_XI) {
        const float* xrow = xi + row * G3;
        xr = xrow[j]; xz = xrow[HD + j]; xn = xrow[2*HD + j];
    } else {
        const float* xp = xsrc + row * HD;
        const float* ur = Wi + (size_t)j * HD;
        const float* uz = Wi + (size_t)(HD + j) * HD;
        const float* un = Wi + (size_t)(2*HD + j) * HD;
        float4 xar = {0,0,0,0}, xaz = {0,0,0,0}, xan = {0,0,0,0};
#pragma unroll 4
        for (int k = 0; k < HD; k += 4) {
            float4 x4 = *(const float4*)(xp + k);
            float4 r4 = *(const float4*)(ur + k);
            float4 z4 = *(const float4*)(uz + k);
            float4 n4 = *(const float4*)(un + k);
            xar.x = fmaf(x4.x, r4.x, xar.x); xar.y = fmaf(x4.y, r4.y, xar.y);
            xar.z = fmaf(x4.z, r4.z, xar.z); xar.w = fmaf(x4.w, r4.w, xar.w);
            xaz.x = fmaf(x4.x, z4.x, xaz.x); xaz.y = fmaf(x4.y, z4.y, xaz.y);
            xaz.z = fmaf(x4.z, z4.z, xaz.z); xaz.w = fmaf(x4.w, z4.w, xaz.w);
            xan.x = fmaf(x4.x, n4.x, xan.x); xan.y = fmaf(x4.y, n4.y, xan.y);
            xan.z = fmaf(x4.z, n4.z, xan.z); xan.w = fmaf(x4.w, n4.w, xan.w);
        }
        xr = (xar.x + xar.y) + (xar.z + xar.w) + bi[j];
        xz = (xaz.x + xaz.y) + (xaz.z + xaz.w) + bi[HD + j];
        xn = (xan.x + xan.y) + (xan.z + xan.w) + bi[2*HD + j];
    }

    float hr = dr + bh[j];
    float hz = dz + bh[HD + j];
    float hn = dn + bh[2*HD + j];
    float r  = sigmoidf_(xr + hr);
    float z  = sigmoidf_(xz + hz);
    float n  = tanhf(xn + r * hn);
    float hpv  = hp[j];
    float hnew = z * hpv + (1.0f - z) * n;

    hnext[(size_t)b * HD + j] = hnew;
    y[row * HD + j]           = hnew;
}

__global__ __launch_bounds__(256) void copy_h(float* __restrict__ dst, int dstride,
                                              const float* __restrict__ src, int sstride)
{
    const int b = blockIdx.x;
    const int t = threadIdx.x;
    *(float4*)(dst + (size_t)b * dstride + t * 4) =
        *(const float4*)(src + (size_t)b * sstride + t * 4);
}

// ---------------------------------------------------------------------------
extern "C" void kernel_launch(void* const* d_in, const int* in_sizes, int n_in,
                              void* d_out, int out_size, void* d_ws, size_t ws_size,
                              hipStream_t stream)
{
    const float* x  = (const float*)d_in[0];   // [32,512,1024]
    const float* h0 = (const float*)d_in[1];   // [32,2,1024]
    const float* Wi = (const float*)d_in[2];   // [2,3072,1024]
    const float* bi = (const float*)d_in[3];   // [2,3072]
    const float* Wh = (const float*)d_in[4];   // [2,3072,1024]
    const float* bh = (const float*)d_in[5];   // [2,3072]

    float* y   = (float*)d_out;                // [32,512,1024]
    float* fin = y + (size_t)MR * HD;          // [32,2,1024]

    const size_t xi_elems   = (size_t)MR * G3;     // ~201MB
    const size_t hbuf_elems = (size_t)NB * HD;     // 32768
    const size_t need_persist = 4096 + (xi_elems + 2 * hbuf_elems) * sizeof(float);

    if (ws_size >= need_persist) {
        unsigned* counters = (unsigned*)d_ws;      // [2][512] uints, 64B-spread
        float* xi  = (float*)((char*)d_ws + 4096);
        float* hb0 = xi + xi_elems;
        float* hb1 = hb0 + hbuf_elems;
        hipMemsetAsync(d_ws, 0, 4096, stream);

        for (int l = 0; l < 2; ++l) {
            const float* src  = (l == 0) ? x : (const float*)y;
            const float* Wi_l = Wi + (size_t)l * G3 * HD;
            const float* bi_l = bi + (size_t)l * G3;
            const float* Wh_l = Wh + (size_t)l * G3 * HD;
            const float* bh_l = bh + (size_t)l * G3;

            gemm_xi<<<dim3(128, 24), 256, 0, stream>>>(src, Wi_l, bi_l, xi);
            gru_persist2<<<PBLK2, 256, 0, stream>>>(xi, Wh_l, bh_l, h0, y, fin,
                                                    hb0, hb1, counters + l * 512, l);
        }
        return;
    }

    // ---------------- fallback: per-step launches ---------------------------
    float* xi = nullptr;
    float* hA;
    if (ws_size >= (xi_elems + 2 * hbuf_elems) * sizeof(float)) {
        xi = (float*)d_ws;
        hA = xi + xi_elems;
    } else {
        hA = (float*)d_ws;
    }
    float* hB = hA + hbuf_elems;

    for (int l = 0; l < 2; ++l) {
        const float* src = (l == 0) ? x : (const float*)y;
        const float* Wi_l = Wi + (size_t)l * G3 * HD;
        const float* bi_l = bi + (size_t)l * G3;
        const float* Wh_l = Wh + (size_t)l * G3 * HD;
        const float* bh_l = bh + (size_t)l * G3;

        if (xi != nullptr)
            gemm_xi<<<dim3(128, 24), 256, 0, stream>>>(src, Wi_l, bi_l, xi);

        copy_h<<<NB, 256, 0, stream>>>(hA, HD, h0 + (size_t)l * HD, 2 * HD);

        float* hp = hA;
        float* hn = hB;
        for (int tt = 0; tt < SEQ; ++tt) {
            if (xi != nullptr)
                gru_step<true><<<128, 256, 0, stream>>>(xi, src, Wi_l, bi_l, Wh_l, bh_l,
                                                        hp, hn, y, tt);
            else
                gru_step<false><<<128, 256, 0, stream>>>(nullptr, src, Wi_l, bi_l, Wh_l, bh_l,
                                                         hp, hn, y, tt);
            float* tmp = hp; hp = hn; hn = tmp;
        }
        copy_h<<<NB, 256, 0, stream>>>(fin + (size_t)l * HD, 2 * HD, hp, HD);
    }
}

// Round 7
// 18506.752 us; speedup vs baseline: 5.3877x; 1.1010x over previous
//
#include <hip/hip_runtime.h>

#define HD    1024
#define SEQ   512
#define NB    32
#define G3    3072          // 3*HD
#define MR    16384         // NB*SEQ
#define PBLK3 256           // persistent grid: 1 block per CU (LDS-forced)

__device__ __forceinline__ float sigmoidf_(float v) { return 1.0f / (1.0f + __expf(-v)); }

// DPP-based wave64 sum reduction: VALU pipe only.
#define DPP_XADD(acc, ctrl, rmask)                                              \
    acc += __int_as_float(__builtin_amdgcn_update_dpp(                          \
        0, __float_as_int(acc), ctrl, rmask, 0xf, false))

__device__ __forceinline__ float wave_reduce_sum(float a)
{
    DPP_XADD(a, 0xB1,  0xF);   // + lane^1
    DPP_XADD(a, 0x4E,  0xF);   // + lane^2
    DPP_XADD(a, 0x141, 0xF);   // row_half_mirror
    DPP_XADD(a, 0x140, 0xF);   // row_mirror
    DPP_XADD(a, 0x142, 0xA);   // row_bcast15 -> rows 1,3
    DPP_XADD(a, 0x143, 0xC);   // row_bcast31 -> rows 2,3
    return __int_as_float(__builtin_amdgcn_readlane(__float_as_int(a), 63));
}

// ---------------------------------------------------------------------------
// xi GEMM (unchanged): C[m][g] = sum_k A[m][k]*W[g][k] + bias[g]
// ---------------------------------------------------------------------------
__global__ __launch_bounds__(256, 2) void gemm_xi(const float* __restrict__ A,
                                                  const float* __restrict__ W,
                                                  const float* __restrict__ bias,
                                                  float* __restrict__ C)
{
    __shared__ float As[16][132];
    __shared__ float Ws[16][132];

    const int t  = threadIdx.x;
    const int m0 = blockIdx.x * 128;
    const int n0 = blockIdx.y * 128;
    const int tx = t & 15;
    const int ty = t >> 4;
    const int lr = t >> 2;
    const int kq = t & 3;

    float acc[8][8];
#pragma unroll
    for (int i = 0; i < 8; ++i)
#pragma unroll
        for (int j = 0; j < 8; ++j) acc[i][j] = 0.0f;

    const float* Ap = A + (size_t)(m0 + lr) * HD + kq * 4;
    const float* Wp = W + (size_t)(n0 + lr) * HD + kq * 4;

    for (int k0 = 0; k0 < HD; k0 += 16) {
        float4 a0 = *(const float4*)(Ap + k0);
        float4 a1 = *(const float4*)(Ap + (size_t)64 * HD + k0);
        float4 w0 = *(const float4*)(Wp + k0);
        float4 w1 = *(const float4*)(Wp + (size_t)64 * HD + k0);
        __syncthreads();
        As[kq*4+0][lr]    = a0.x; As[kq*4+1][lr]    = a0.y;
        As[kq*4+2][lr]    = a0.z; As[kq*4+3][lr]    = a0.w;
        As[kq*4+0][lr+64] = a1.x; As[kq*4+1][lr+64] = a1.y;
        As[kq*4+2][lr+64] = a1.z; As[kq*4+3][lr+64] = a1.w;
        Ws[kq*4+0][lr]    = w0.x; Ws[kq*4+1][lr]    = w0.y;
        Ws[kq*4+2][lr]    = w0.z; Ws[kq*4+3][lr]    = w0.w;
        Ws[kq*4+0][lr+64] = w1.x; Ws[kq*4+1][lr+64] = w1.y;
        Ws[kq*4+2][lr+64] = w1.z; Ws[kq*4+3][lr+64] = w1.w;
        __syncthreads();
#pragma unroll
        for (int k = 0; k < 16; ++k) {
            float4 av0 = *(const float4*)(&As[k][ty*8]);
            float4 av1 = *(const float4*)(&As[k][ty*8+4]);
            float4 bv0 = *(const float4*)(&Ws[k][tx*8]);
            float4 bv1 = *(const float4*)(&Ws[k][tx*8+4]);
            float a[8]  = {av0.x, av0.y, av0.z, av0.w, av1.x, av1.y, av1.z, av1.w};
            float bb[8] = {bv0.x, bv0.y, bv0.z, bv0.w, bv1.x, bv1.y, bv1.z, bv1.w};
#pragma unroll
            for (int i = 0; i < 8; ++i)
#pragma unroll
                for (int j = 0; j < 8; ++j)
                    acc[i][j] = fmaf(a[i], bb[j], acc[i][j]);
        }
    }

    float4 bb0 = *(const float4*)(bias + n0 + tx*8);
    float4 bb1 = *(const float4*)(bias + n0 + tx*8 + 4);
    const float bv[8] = {bb0.x, bb0.y, bb0.z, bb0.w, bb1.x, bb1.y, bb1.z, bb1.w};
#pragma unroll
    for (int i = 0; i < 8; ++i) {
        float* crow = C + (size_t)(m0 + ty*8 + i) * G3 + n0 + tx*8;
        float4 o0 = {acc[i][0]+bv[0], acc[i][1]+bv[1], acc[i][2]+bv[2], acc[i][3]+bv[3]};
        float4 o1 = {acc[i][4]+bv[4], acc[i][5]+bv[5], acc[i][6]+bv[6], acc[i][7]+bv[7]};
        *(float4*)(crow)     = o0;
        *(float4*)(crow + 4) = o1;
    }
}

// ---------------------------------------------------------------------------
// Persistent GRU v3. Grid 256 (1 block/CU, forced by 129.5KB LDS) x 512 thr
// (8 waves = 2/SIMD). Block owns 4 j-columns and ALL 32 batches ->
// h-broadcast traffic halves vs v2 (256 x 128KB = 16MB/step).
// Wave w: column jc=w>>1 (j = bk*4+jc), batch half (w&1); 3 gate rows in 48
// VGPRs (lane l holds k=256c+4l..+3, contiguous 16B -> conflict-free
// ds_read_b128). DPP reduce. Barrier: 32 spread counters x 8 blocks.
// ---------------------------------------------------------------------------
__global__ __launch_bounds__(512, 1) void gru_persist3(const float* __restrict__ xi,
                                                       const float* __restrict__ Wh,
                                                       const float* __restrict__ bh,
                                                       const float* __restrict__ h0,
                                                       float* __restrict__ y,
                                                       float* __restrict__ fin,
                                                       float* __restrict__ hb0,
                                                       float* __restrict__ hb1,
                                                       unsigned* __restrict__ cnt,
                                                       int layer)
{
    __shared__ float  hs[NB * HD];     // full 32-batch h state, 128 KB
    __shared__ float4 xis[3][NB];      // xi for (gate, batch) x this block's 4 j's

    const int tid  = threadIdx.x;
    const int bk   = blockIdx.x;
    const int w    = tid >> 6;         // wave 0..7
    const int lane = tid & 63;
    const int jc   = w >> 1;           // 0..3: which of the block's 4 columns
    const int half = w & 1;            // batch half
    const int j    = bk * 4 + jc;

    // --- weights into registers (lane l: k = 256c + 4l, contiguous 16B) ---
    float4 w0[4], w1[4], w2[4];
#pragma unroll
    for (int c = 0; c < 4; ++c) {
        w0[c] = *(const float4*)(Wh + (size_t)j          * HD + 256*c + 4*lane);
        w1[c] = *(const float4*)(Wh + (size_t)(HD + j)   * HD + 256*c + 4*lane);
        w2[c] = *(const float4*)(Wh + (size_t)(2*HD + j) * HD + 256*c + 4*lane);
    }
    const float bhr = bh[j], bhz = bh[HD + j], bhn = bh[2*HD + j];

    for (int t = 0; t < SEQ; ++t) {
        // ---- stage h (all 32 batches) + xi into LDS ----
        if (t == 0) {
            const int r = tid >> 4, pc = tid & 15;   // 32 rows x 16 thr
            const float* src = h0 + (size_t)r * (2*HD) + (size_t)layer * HD;
#pragma unroll
            for (int cc = 0; cc < 16; ++cc) {
                const int f4 = pc * 16 + cc;
                *(float4*)(hs + (size_t)r * HD + f4 * 4) =
                    *(const float4*)(src + f4 * 4);
            }
        } else {
            const float* src = (t & 1) ? hb0 : hb1;
#pragma unroll
            for (int c = 0; c < 16; ++c) {
                const int f4 = c * 512 + tid;        // coalesced, covers 32K floats
                *(float4*)(hs + f4 * 4) = *(const float4*)(src + f4 * 4);
            }
        }
        if (tid < 96) {
            const int g = tid >> 5, bl = tid & 31;
            xis[g][bl] = *(const float4*)(xi + ((size_t)bl * SEQ + t) * G3
                                             + g * HD + bk * 4);
        }
        __syncthreads();

        float* hbw = (t & 1) ? hb1 : hb0;

#pragma unroll 4
        for (int i = 0; i < 16; ++i) {
            const int b = half * 16 + i;
            const float* hp = hs + (size_t)b * HD;
            float ar = 0.f, az = 0.f, an = 0.f;
#pragma unroll
            for (int c = 0; c < 4; ++c) {
                float4 hq = *(const float4*)(hp + 256*c + 4*lane);
                ar = fmaf(w0[c].x, hq.x, ar); ar = fmaf(w0[c].y, hq.y, ar);
                ar = fmaf(w0[c].z, hq.z, ar); ar = fmaf(w0[c].w, hq.w, ar);
                az = fmaf(w1[c].x, hq.x, az); az = fmaf(w1[c].y, hq.y, az);
                az = fmaf(w1[c].z, hq.z, az); az = fmaf(w1[c].w, hq.w, az);
                an = fmaf(w2[c].x, hq.x, an); an = fmaf(w2[c].y, hq.y, an);
                an = fmaf(w2[c].z, hq.z, an); an = fmaf(w2[c].w, hq.w, an);
            }
            const float sr = wave_reduce_sum(ar);
            const float sz = wave_reduce_sum(az);
            const float sn = wave_reduce_sum(an);

            const float xr = ((const float*)&xis[0][b])[jc];
            const float xz = ((const float*)&xis[1][b])[jc];
            const float xn = ((const float*)&xis[2][b])[jc];

            const float rr  = sigmoidf_(xr + sr + bhr);
            const float zz  = sigmoidf_(xz + sz + bhz);
            const float hpv = hp[j];
            const float e   = __expf(2.0f * (xn + rr * (sn + bhn)));
            const float nn  = 1.0f - 2.0f / (e + 1.0f);          // tanh
            const float hnew = zz * hpv + (1.0f - zz) * nn;

            if (lane == 0) {
                __hip_atomic_store(hbw + (size_t)b * HD + j, hnew,
                                   __ATOMIC_RELAXED, __HIP_MEMORY_SCOPE_AGENT);
                y[((size_t)b * SEQ + t) * HD + j] = hnew;
                if (t == SEQ - 1)
                    fin[((size_t)b * 2 + layer) * HD + j] = hnew;
            }
        }

        if (t < SEQ - 1) {
            __syncthreads();                    // drains vmcnt: stores visible
            if (tid == 0)
                __hip_atomic_fetch_add(cnt + (bk & 31) * 16, 1u,
                                       __ATOMIC_RELAXED, __HIP_MEMORY_SCOPE_AGENT);
            if (tid < 64) {                     // wave 0 polls all 32 counters
                const unsigned tgt = 8u * (unsigned)(t + 1);
                for (;;) {
                    unsigned v = tgt;
                    if (lane < 32)
                        v = __hip_atomic_load(cnt + lane * 16, __ATOMIC_RELAXED,
                                              __HIP_MEMORY_SCOPE_AGENT);
                    if (__all((int)(v >= tgt))) break;
                    __builtin_amdgcn_s_sleep(2);
                }
                __builtin_amdgcn_fence(__ATOMIC_ACQUIRE, "agent");  // inv L1/L2
            }
            __syncthreads();
        }
    }
}

// --------------------------- fallback path (small ws) -----------------------
template <bool USE_XI>
__global__ __launch_bounds__(256) void gru_step(const float* __restrict__ xi,
                                                const float* __restrict__ xsrc,
                                                const float* __restrict__ Wi,
                                                const float* __restrict__ bi,
                                                const float* __restrict__ Wh,
                                                const float* __restrict__ bh,
                                                const float* __restrict__ hprev,
                                                float* __restrict__ hnext,
                                                float* __restrict__ y,
                                                int t)
{
    const int tid = threadIdx.x;
    const int b   = tid >> 3;
    const int jc  = tid & 7;
    const int j   = blockIdx.x * 8 + jc;

    const float* hp = hprev + (size_t)b * HD;
    const float* wr = Wh + (size_t)j * HD;
    const float* wz = Wh + (size_t)(HD + j) * HD;
    const float* wn = Wh + (size_t)(2*HD + j) * HD;

    float4 ar = {0,0,0,0}, az = {0,0,0,0}, an = {0,0,0,0};
#pragma unroll 4
    for (int k = 0; k < HD; k += 4) {
        float4 h4 = *(const float4*)(hp + k);
        float4 r4 = *(const float4*)(wr + k);
        float4 z4 = *(const float4*)(wz + k);
        float4 n4 = *(const float4*)(wn + k);
        ar.x = fmaf(h4.x, r4.x, ar.x); ar.y = fmaf(h4.y, r4.y, ar.y);
        ar.z = fmaf(h4.z, r4.z, ar.z); ar.w = fmaf(h4.w, r4.w, ar.w);
        az.x = fmaf(h4.x, z4.x, az.x); az.y = fmaf(h4.y, z4.y, az.y);
        az.z = fmaf(h4.z, z4.z, az.z); az.w = fmaf(h4.w, z4.w, az.w);
        an.x = fmaf(h4.x, n4.x, an.x); an.y = fmaf(h4.y, n4.y, an.y);
        an.z = fmaf(h4.z, n4.z, an.z); an.w = fmaf(h4.w, n4.w, an.w);
    }
    float dr = (ar.x + ar.y) + (ar.z + ar.w);
    float dz = (az.x + az.y) + (az.z + az.w);
    float dn = (an.x + an.y) + (an.z + an.w);

    const size_t row = (size_t)b * SEQ + t;
    float xr, xz, xn;
    if (USE_XI) {
        const float* xrow = xi + row * G3;
        xr = xrow[j]; xz = xrow[HD + j]; xn = xrow[2*HD + j];
    } else {
        const float* xp = xsrc + row * HD;
        const float* ur = Wi + (size_t)j * HD;
        const float* uz = Wi + (size_t)(HD + j) * HD;
        const float* un = Wi + (size_t)(2*HD + j) * HD;
        float4 xar = {0,0,0,0}, xaz = {0,0,0,0}, xan = {0,0,0,0};
#pragma unroll 4
        for (int k = 0; k < HD; k += 4) {
            float4 x4 = *(const float4*)(xp + k);
            float4 r4 = *(const float4*)(ur + k);
            float4 z4 = *(const float4*)(uz + k);
            float4 n4 = *(const float4*)(un + k);
            xar.x = fmaf(x4.x, r4.x, xar.x); xar.y = fmaf(x4.y, r4.y, xar.y);
            xar.z = fmaf(x4.z, r4.z, xar.z); xar.w = fmaf(x4.w, r4.w, xar.w);
            xaz.x = fmaf(x4.x, z4.x, xaz.x); xaz.y = fmaf(x4.y, z4.y, xaz.y);
            xaz.z = fmaf(x4.z, z4.z, xaz.z); xaz.w = fmaf(x4.w, z4.w, xaz.w);
            xan.x = fmaf(x4.x, n4.x, xan.x); xan.y = fmaf(x4.y, n4.y, xan.y);
            xan.z = fmaf(x4.z, n4.z, xan.z); xan.w = fmaf(x4.w, n4.w, xan.w);
        }
        xr = (xar.x + xar.y) + (xar.z + xar.w) + bi[j];
        xz = (xaz.x + xaz.y) + (xaz.z + xaz.w) + bi[HD + j];
        xn = (xan.x + xan.y) + (xan.z + xan.w) + bi[2*HD + j];
    }

    float hr = dr + bh[j];
    float hz = dz + bh[HD + j];
    float hn = dn + bh[2*HD + j];
    float r  = sigmoidf_(xr + hr);
    float z  = sigmoidf_(xz + hz);
    float n  = tanhf(xn + r * hn);
    float hpv  = hp[j];
    float hnew = z * hpv + (1.0f - z) * n;

    hnext[(size_t)b * HD + j] = hnew;
    y[row * HD + j]           = hnew;
}

__global__ __launch_bounds__(256) void copy_h(float* __restrict__ dst, int dstride,
                                              const float* __restrict__ src, int sstride)
{
    const int b = blockIdx.x;
    const int t = threadIdx.x;
    *(float4*)(dst + (size_t)b * dstride + t * 4) =
        *(const float4*)(src + (size_t)b * sstride + t * 4);
}

// ---------------------------------------------------------------------------
extern "C" void kernel_launch(void* const* d_in, const int* in_sizes, int n_in,
                              void* d_out, int out_size, void* d_ws, size_t ws_size,
                              hipStream_t stream)
{
    const float* x  = (const float*)d_in[0];   // [32,512,1024]
    const float* h0 = (const float*)d_in[1];   // [32,2,1024]
    const float* Wi = (const float*)d_in[2];   // [2,3072,1024]
    const float* bi = (const float*)d_in[3];   // [2,3072]
    const float* Wh = (const float*)d_in[4];   // [2,3072,1024]
    const float* bh = (const float*)d_in[5];   // [2,3072]

    float* y   = (float*)d_out;                // [32,512,1024]
    float* fin = y + (size_t)MR * HD;          // [32,2,1024]

    const size_t xi_elems   = (size_t)MR * G3;     // ~201MB
    const size_t hbuf_elems = (size_t)NB * HD;     // 32768
    const size_t need_persist = 4096 + (xi_elems + 2 * hbuf_elems) * sizeof(float);

    if (ws_size >= need_persist) {
        unsigned* counters = (unsigned*)d_ws;      // [2][512] uints, 64B-spread
        float* xi  = (float*)((char*)d_ws + 4096);
        float* hb0 = xi + xi_elems;
        float* hb1 = hb0 + hbuf_elems;
        hipMemsetAsync(d_ws, 0, 4096, stream);

        for (int l = 0; l < 2; ++l) {
            const float* src  = (l == 0) ? x : (const float*)y;
            const float* Wi_l = Wi + (size_t)l * G3 * HD;
            const float* bi_l = bi + (size_t)l * G3;
            const float* Wh_l = Wh + (size_t)l * G3 * HD;
            const float* bh_l = bh + (size_t)l * G3;

            gemm_xi<<<dim3(128, 24), 256, 0, stream>>>(src, Wi_l, bi_l, xi);
            gru_persist3<<<PBLK3, 512, 0, stream>>>(xi, Wh_l, bh_l, h0, y, fin,
                                                    hb0, hb1, counters + l * 512, l);
        }
        return;
    }

    // ---------------- fallback: per-step launches ---------------------------
    float* xi = nullptr;
    float* hA;
    if (ws_size >= (xi_elems + 2 * hbuf_elems) * sizeof(float)) {
        xi = (float*)d_ws;
        hA = xi + xi_elems;
    } else {
        hA = (float*)d_ws;
    }
    float* hB = hA + hbuf_elems;

    for (int l = 0; l < 2; ++l) {
        const float* src = (l == 0) ? x : (const float*)y;
        const float* Wi_l = Wi + (size_t)l * G3 * HD;
        const float* bi_l = bi + (size_t)l * G3;
        const float* Wh_l = Wh + (size_t)l * G3 * HD;
        const float* bh_l = bh + (size_t)l * G3;

        if (xi != nullptr)
            gemm_xi<<<dim3(128, 24), 256, 0, stream>>>(src, Wi_l, bi_l, xi);

        copy_h<<<NB, 256, 0, stream>>>(hA, HD, h0 + (size_t)l * HD, 2 * HD);

        float* hp = hA;
        float* hn = hB;
        for (int tt = 0; tt < SEQ; ++tt) {
            if (xi != nullptr)
                gru_step<true><<<128, 256, 0, stream>>>(xi, src, Wi_l, bi_l, Wh_l, bh_l,
                                                        hp, hn, y, tt);
            else
                gru_step<false><<<128, 256, 0, stream>>>(nullptr, src, Wi_l, bi_l, Wh_l, bh_l,
                                                         hp, hn, y, tt);
            float* tmp = hp; hp = hn; hn = tmp;
        }
        copy_h<<<NB, 256, 0, stream>>>(fin + (size_t)l * HD, 2 * HD, hp, HD);
    }
}